// Round 3
// baseline (482.650 us; speedup 1.0000x reference)
//
#include <hip/hip_runtime.h>
#include <stdint.h>

#define NUM_TOKENS 16384
#define DIM        4096
#define NEXP       256
#define MB         32      // tokens per block
#define BK         64      // K per staging step
#define NITER      (DIM / BK)   // 64
#define APAD       72      // A row stride in ushorts (16B-aligned rows, conflict-light)
#define NWAVES     4
#define MARGIN     0.025f  // ~8.6 sigma of the pure-bf16 gap error (std ~2.9e-3)
#define CAP        16384   // refinement list capacity

typedef __attribute__((ext_vector_type(4))) float          f32x4;
typedef __attribute__((ext_vector_type(8))) __bf16         bf16x8;
typedef __attribute__((ext_vector_type(8))) unsigned short ushort8;

static __device__ __forceinline__ unsigned short f32_to_bf16(float f) {
    unsigned int u = __float_as_uint(f);
    u += 0x7fffu + ((u >> 16) & 1u);     // round-to-nearest-even
    return (unsigned short)(u >> 16);
}

// ---------------------------------------------------------------- kernel 1
__global__ void cvt_weights(const float* __restrict__ w,
                            unsigned short* __restrict__ wh,
                            int* __restrict__ counter) {
    if (blockIdx.x == 0 && threadIdx.x == 0) *counter = 0;
    const int n4 = NEXP * DIM / 4;
    const int stride = gridDim.x * blockDim.x;
    for (int i = blockIdx.x * blockDim.x + threadIdx.x; i < n4; i += stride) {
        float4 v = ((const float4*)w)[i];
        ushort4 h;
        h.x = f32_to_bf16(v.x); h.y = f32_to_bf16(v.y);
        h.z = f32_to_bf16(v.z); h.w = f32_to_bf16(v.w);
        ((ushort4*)wh)[i] = h;
    }
}

// ---------------------------------------------------------------- kernel 2
// R3: anti-convoy restructure. Counters showed MfmaUtil 7.9 / VALU 8.0 /
// HBM 10.5% / occ 42% -> latency-bound, not throughput. 6450 cyc/iter vs
// ~600 cyc of work: barrier-locked waves stalled on HBM x (lead only 2
// iters) and L2 B, convoyed through 2 big 8-wave barrier domains per CU.
// Changes: (1) 4-wave blocks (wave = 32tok x 64exp, acc[2][4]) -> 4
// independent barrier domains/CU, 2x MFMA per wave-iter, cross-block L1
// hits on B; (2) x prefetch ring, lead 4 iters; (3) A-tile 4-slot LDS
// ring staged 2 iters ahead (publication off the critical path).
// lgkm-only barriers: the x/B vmem streams stay in flight across them.
__global__ __launch_bounds__(256, 4) void gate_main(
    const float* __restrict__ x,
    const unsigned short* __restrict__ wh,
    float* __restrict__ out,           // [0,T) weights, [T,2T) indices (as float)
    int* __restrict__ counter,
    int4* __restrict__ entries)
{
    __shared__ unsigned short lAh[4][MB][APAD];    // 18 KB: 4-slot A ring
    __shared__ float4 cand[NWAVES][MB];            // 2 KB

    const int tid  = threadIdx.x;
    const int wv   = tid >> 6;          // wave 0..3 -> experts [wv*64, wv*64+64)
    const int lane = tid & 63;
    const int tok0 = blockIdx.x * MB;

    // A staging: thread covers token ta, 8 floats at kc8 (one ushort8 LDS write)
    const int ta  = tid >> 3;           // 0..31
    const int kc8 = (tid & 7) * 8;      // 0..56
    const float* xrow = x + (size_t)(tok0 + ta) * DIM + kc8;

    const int quad = lane >> 4;
    const int col  = lane & 15;

    // B fragment base offset (elements): expert = wv*64 + nt*16 + col
    const int boff = (wv * 64 + col) * DIM + quad * 8;

    f32x4 acc[2][4];
    #pragma unroll
    for (int mt = 0; mt < 2; ++mt)
        #pragma unroll
        for (int nt = 0; nt < 4; ++nt)
            acc[mt][nt] = f32x4{0.f, 0.f, 0.f, 0.f};

    bf16x8 b[2][4];    // [kk2][nt] current-iter B fragments (static idx only)

    struct XQ { float4 lo, hi; };
    auto cvt8 = [](const XQ& v) {
        ushort8 h;
        h[0] = f32_to_bf16(v.lo.x); h[1] = f32_to_bf16(v.lo.y);
        h[2] = f32_to_bf16(v.lo.z); h[3] = f32_to_bf16(v.lo.w);
        h[4] = f32_to_bf16(v.hi.x); h[5] = f32_to_bf16(v.hi.y);
        h[6] = f32_to_bf16(v.hi.z); h[7] = f32_to_bf16(v.hi.w);
        return h;
    };
    auto ldx = [&](int it) {
        XQ v;
        v.lo = *(const float4*)(xrow + it * BK);
        v.hi = *(const float4*)(xrow + it * BK + 4);
        return v;
    };

    // ---- prologue: x(0..5) issued first, then B(0), then stage A(0),A(1).
    XQ t0 = ldx(0), t1 = ldx(1);
    XQ xq2 = ldx(2), xq3 = ldx(3), xq0 = ldx(4), xq1 = ldx(5);
    #pragma unroll
    for (int kk2 = 0; kk2 < 2; ++kk2)
        #pragma unroll
        for (int nt = 0; nt < 4; ++nt)
            b[kk2][nt] = *(const bf16x8*)(wh + boff + nt * (16 * DIM) + kk2 * 32);
    *(ushort8*)&lAh[0][ta][kc8] = cvt8(t0);
    *(ushort8*)&lAh[1][ta][kc8] = cvt8(t1);
    asm volatile("s_waitcnt lgkmcnt(0)" ::: "memory");
    __builtin_amdgcn_s_barrier();
    asm volatile("" ::: "memory");

    // body(it): stage A(it+2) from xq (== x(it+2)), refill xq = x(it+6);
    // compute from ring slot it&3; refill b with B(it+1) right after use.
    auto body = [&](int it, XQ& xq) {
        if (it + 2 < NITER) {
            *(ushort8*)&lAh[(it + 2) & 3][ta][kc8] = cvt8(xq);
            if (it + 6 < NITER)
                xq = ldx(it + 6);
        }
        const int s = it & 3;
        #pragma unroll
        for (int kk2 = 0; kk2 < 2; ++kk2) {
            bf16x8 ah0 = *(const bf16x8*)&lAh[s][col][kk2 * 32 + quad * 8];
            bf16x8 ah1 = *(const bf16x8*)&lAh[s][16 + col][kk2 * 32 + quad * 8];
            #pragma unroll
            for (int nt = 0; nt < 4; ++nt) {
                acc[0][nt] = __builtin_amdgcn_mfma_f32_16x16x32_bf16(ah0, b[kk2][nt], acc[0][nt], 0, 0, 0);
                acc[1][nt] = __builtin_amdgcn_mfma_f32_16x16x32_bf16(ah1, b[kk2][nt], acc[1][nt], 0, 0, 0);
            }
            if (it + 1 < NITER) {       // refill after use: ~1 iter lead into it+1
                #pragma unroll
                for (int nt = 0; nt < 4; ++nt)
                    b[kk2][nt] = *(const bf16x8*)(wh + boff + nt * (16 * DIM)
                                                  + (it + 1) * BK + kk2 * 32);
            }
        }
        asm volatile("s_waitcnt lgkmcnt(0)" ::: "memory");  // publish A(it+2)
        __builtin_amdgcn_s_barrier();
        asm volatile("" ::: "memory");
    };

    #pragma unroll 1
    for (int itb = 0; itb < NITER; itb += 4) {
        body(itb + 0, xq2);   // stages A(itb+2) <- xq2, reloads x(itb+6)
        body(itb + 1, xq3);
        body(itb + 2, xq0);
        body(itb + 3, xq1);
    }

    // ---- epilogue: per-wave top-2 over its 64 experts, per token.
    // C/D layout (16x16): col = lane&15 (expert), row = quad*4 + reg (token).
    #pragma unroll
    for (int mt = 0; mt < 2; ++mt) {
        #pragma unroll
        for (int r = 0; r < 4; ++r) {
            float t1s = acc[mt][0][r]; int t1e = wv * 64 + col;
            float t2s = -__builtin_inff(); int t2e = 0x7fffffff;
            #pragma unroll
            for (int nt = 1; nt < 4; ++nt) {
                float s = acc[mt][nt][r]; int e = wv * 64 + nt * 16 + col;
                if (s > t1s) {          // e > t1e always, so ties keep t1
                    t2s = t1s; t2e = t1e; t1s = s; t1e = e;
                } else if (s > t2s || (s == t2s && e < t2e)) {
                    t2s = s; t2e = e;
                }
            }
            #pragma unroll
            for (int m = 1; m <= 8; m <<= 1) {
                float o1s = __shfl_xor(t1s, m); int o1e = __shfl_xor(t1e, m);
                float o2s = __shfl_xor(t2s, m); int o2e = __shfl_xor(t2e, m);
                bool o1_top = (o1s > t1s) || (o1s == t1s && o1e < t1e);
                if (o1_top) {
                    bool keep_t1 = (t1s > o2s) || (t1s == o2s && t1e < o2e);
                    t2s = keep_t1 ? t1s : o2s; t2e = keep_t1 ? t1e : o2e;
                    t1s = o1s; t1e = o1e;
                } else {
                    bool o1_2nd = (o1s > t2s) || (o1s == t2s && o1e < t2e);
                    if (o1_2nd) { t2s = o1s; t2e = o1e; }
                }
            }
            if (col == 0) {
                int tok = mt * 16 + quad * 4 + r;
                cand[wv][tok] = make_float4(t1s, __int_as_float(t1e), t2s, __int_as_float(t2e));
            }
        }
    }
    __syncthreads();

    // ---- final merge across waves; write outputs + near-tie flags
    if (tid < MB) {
        float4 c0 = cand[0][tid];
        float t1s = c0.x; int t1e = __float_as_int(c0.y);
        float t2s = c0.z; int t2e = __float_as_int(c0.w);
        #pragma unroll
        for (int wvi = 1; wvi < NWAVES; ++wvi) {
            float4 c = cand[wvi][tid];
            float o1s = c.x; int o1e = __float_as_int(c.y);
            float o2s = c.z; int o2e = __float_as_int(c.w);
            bool o1_top = (o1s > t1s) || (o1s == t1s && o1e < t1e);
            if (o1_top) {
                bool keep_t1 = (t1s > o2s) || (t1s == o2s && t1e < o2e);
                t2s = keep_t1 ? t1s : o2s; t2e = keep_t1 ? t1e : o2e;
                t1s = o1s; t1e = o1e;
            } else {
                bool o1_2nd = (o1s > t2s) || (o1s == t2s && o1e < t2e);
                if (o1_2nd) { t2s = o1s; t2e = o1e; }
            }
        }
        const int gtok = tok0 + tid;
        out[gtok] = 1.0f;                       // STE forward value at argmax
        out[NUM_TOKENS + gtok] = (float)t1e;    // index as float
        if (t1s - t2s < MARGIN) {
            int slot = atomicAdd(counter, 1);
            if (slot < CAP) entries[slot] = make_int4(gtok, t1e, t2e, 0);
        }
    }
}

// ---------------------------------------------------------------- kernel 3
// fp64 re-verification of near-tie tokens (one wave per flagged token).
__global__ void refine(const float* __restrict__ x,
                       const float* __restrict__ w,
                       const int* __restrict__ counter,
                       const int4* __restrict__ entries,
                       float* __restrict__ out) {
    const int gwave  = (blockIdx.x * blockDim.x + threadIdx.x) >> 6;
    const int lane   = threadIdx.x & 63;
    const int nwaves = (gridDim.x * blockDim.x) >> 6;
    int n = *counter; if (n > CAP) n = CAP;
    for (int i = gwave; i < n; i += nwaves) {
        int4 e = entries[i];
        const float* xr = x + (size_t)e.x * DIM;
        const float* w1 = w + (size_t)e.y * DIM;
        const float* w2 = w + (size_t)e.z * DIM;
        double d1 = 0.0, d2 = 0.0;
        for (int k = lane; k < DIM; k += 64) {
            double xv = (double)xr[k];
            d1 += xv * (double)w1[k];
            d2 += xv * (double)w2[k];
        }
        #pragma unroll
        for (int m = 32; m > 0; m >>= 1) {
            d1 += __shfl_xor(d1, m);
            d2 += __shfl_xor(d2, m);
        }
        if (lane == 0) {
            int best = (d1 > d2) ? e.y : ((d2 > d1) ? e.z : (e.y < e.z ? e.y : e.z));
            out[NUM_TOKENS + e.x] = (float)best;
        }
    }
}

// ---------------------------------------------------------------- launcher
extern "C" void kernel_launch(void* const* d_in, const int* in_sizes, int n_in,
                              void* d_out, int out_size, void* d_ws, size_t ws_size,
                              hipStream_t stream) {
    const float* x = (const float*)d_in[0];
    const float* w = (const float*)d_in[1];
    float* out = (float*)d_out;

    char* ws = (char*)d_ws;
    unsigned short* wh = (unsigned short*)ws;                     // 2 MB
    int*  counter = (int*)(ws + (2u << 20));
    int4* entries = (int4*)(ws + (2u << 20) + 16);                // 256 KB

    cvt_weights<<<256, 256, 0, stream>>>(w, wh, counter);
    gate_main<<<NUM_TOKENS / MB, 256, 0, stream>>>(x, wh, out, counter, entries);
    refine<<<256, 256, 0, stream>>>(x, w, counter, entries, out);
}

// Round 4
// 462.220 us; speedup vs baseline: 1.0442x; 1.0442x over previous
//
#include <hip/hip_runtime.h>
#include <stdint.h>

#define NUM_TOKENS 16384
#define DIM        4096
#define NEXP       256
#define MB         32      // tokens per block
#define BK         64      // K per staging step
#define NITER      (DIM / BK)   // 64
#define APAD       72      // A row stride (+8 kills bank conflicts, keeps 16B align)
#define NWAVES     8
#define MARGIN     0.025f  // ~8.6 sigma of the pure-bf16 gap error (std ~2.9e-3)
#define CAP        16384   // refinement list capacity

typedef __attribute__((ext_vector_type(4))) float   f32x4;
typedef __attribute__((ext_vector_type(8))) __bf16  bf16x8;

static __device__ __forceinline__ unsigned short f32_to_bf16(float f) {
    unsigned int u = __float_as_uint(f);
    u += 0x7fffu + ((u >> 16) & 1u);     // round-to-nearest-even
    return (unsigned short)(u >> 16);
}

// ---------------------------------------------------------------- kernel 1
__global__ void cvt_weights(const float* __restrict__ w,
                            unsigned short* __restrict__ wh,
                            int* __restrict__ counter) {
    if (blockIdx.x == 0 && threadIdx.x == 0) *counter = 0;
    const int n4 = NEXP * DIM / 4;
    const int stride = gridDim.x * blockDim.x;
    for (int i = blockIdx.x * blockDim.x + threadIdx.x; i < n4; i += stride) {
        float4 v = ((const float4*)w)[i];
        ushort4 h;
        h.x = f32_to_bf16(v.x); h.y = f32_to_bf16(v.y);
        h.z = f32_to_bf16(v.z); h.w = f32_to_bf16(v.w);
        ((ushort4*)wh)[i] = h;
    }
}

// ---------------------------------------------------------------- kernel 2
// R4: vmcnt in-order-retirement fix. R2/R3 post-mortem: all pipes <12%,
// occupancy-independent (42%->21% cost only 15%) -> per-wave serial stall.
// Mechanism: vmcnt retires IN ISSUE ORDER (m135). R2/R3 issued the HBM x
// prefetch BEFORE the L2 b refills each iter; consuming b next iter then
// forces retirement of the ~900-cyc x load issued ~1 iter earlier. Every
// iteration pays ~an HBM latency; deeper x rings made it WORSE (fresher x
// in front of b) - exactly R3's regression.
// Fix: (1) b refills are 2-iters-ahead ping-pong (bA/bB) so consumed-b is
// always OLDER than any in-flight x; (2) x ring refill moves to the END of
// the body (after all b issues, pinned by sched_barrier). x is then only
// force-retired at age ~3 iters (>= HBM latency). Structure otherwise = R2:
// 512 thr / 8 waves, wave = 32 tok x 32 exp, A dbuf in LDS, lgkm-only
// barriers.
__global__ __launch_bounds__(512, 4) void gate_main(
    const float* __restrict__ x,
    const unsigned short* __restrict__ wh,
    float* __restrict__ out,           // [0,T) weights, [T,2T) indices (as float)
    int* __restrict__ counter,
    int4* __restrict__ entries)
{
    __shared__ unsigned short lAh[2][MB][APAD];    // 2 x 4.5 KB
    __shared__ float4 cand[NWAVES][MB];            // 4 KB

    const int tid  = threadIdx.x;
    const int wv   = tid >> 6;          // wave 0..7 -> experts [wv*32, wv*32+32)
    const int lane = tid & 63;
    const int tok0 = blockIdx.x * MB;

    // A staging: thread covers token ta, 4 floats at kcol
    const int ta   = tid >> 4;          // 0..31
    const int kcol = (tid & 15) * 4;    // 0..60
    const float* xrow = x + (size_t)(tok0 + ta) * DIM + kcol;

    const int quad = lane >> 4;
    const int col  = lane & 15;

    // per-lane B fragment pointers: expert e = wv*32 + nt*16 + col, k base quad*8.
    const unsigned short* bp[2];
    #pragma unroll
    for (int nt = 0; nt < 2; ++nt)
        bp[nt] = wh + (size_t)(wv * 32 + nt * 16 + col) * DIM + quad * 8;

    f32x4 acc[2][2];
    #pragma unroll
    for (int mt = 0; mt < 2; ++mt)
        #pragma unroll
        for (int nt = 0; nt < 2; ++nt)
            acc[mt][nt] = f32x4{0.f, 0.f, 0.f, 0.f};

    // ---- prologue. ISSUE ORDER IS THE POINT: b(0), b(1) first, THEN x.
    bf16x8 b0[2][2], b1[2][2];          // ping-pong B sets (static idx only)
    #pragma unroll
    for (int kk2 = 0; kk2 < 2; ++kk2)
        #pragma unroll
        for (int nt = 0; nt < 2; ++nt)
            b0[kk2][nt] = *(const bf16x8*)(bp[nt] + kk2 * 32);            // b(0)
    #pragma unroll
    for (int kk2 = 0; kk2 < 2; ++kk2)
        #pragma unroll
        for (int nt = 0; nt < 2; ++nt)
            b1[kk2][nt] = *(const bf16x8*)(bp[nt] + BK + kk2 * 32);       // b(1)
    __builtin_amdgcn_sched_barrier(0);   // keep x issues AFTER the b issues
    float4 x0 = *(const float4*)(xrow);              // x(0)
    float4 r0 = *(const float4*)(xrow + 1 * BK);     // x(1)
    float4 r1 = *(const float4*)(xrow + 2 * BK);     // x(2)
    float4 r2 = *(const float4*)(xrow + 3 * BK);     // x(3)
    float4 r3 = *(const float4*)(xrow + 4 * BK);     // x(4)
    {
        ushort4 h;
        h.x = f32_to_bf16(x0.x); h.y = f32_to_bf16(x0.y);
        h.z = f32_to_bf16(x0.z); h.w = f32_to_bf16(x0.w);
        *(ushort4*)&lAh[0][ta][kcol] = h;            // waits x(0) only (vmcnt(4))
    }
    asm volatile("s_waitcnt lgkmcnt(0)" ::: "memory");
    __builtin_amdgcn_s_barrier();
    asm volatile("" ::: "memory");

    // body(it): consume bc == b(it); refill bc with b(it+2) after use (2-ahead);
    // stage A(it+1) from xr == x(it+1); refill xr with x(it+5) at the END.
    auto body = [&](int it, float4& xr, bf16x8 (&bc)[2][2]) {
        const int cur = it & 1;
        const int nxt = cur ^ 1;
        if (it + 1 < NITER) {
            ushort4 h;
            h.x = f32_to_bf16(xr.x); h.y = f32_to_bf16(xr.y);
            h.z = f32_to_bf16(xr.z); h.w = f32_to_bf16(xr.w);
            *(ushort4*)&lAh[nxt][ta][kcol] = h;
        }
        #pragma unroll
        for (int kk2 = 0; kk2 < 2; ++kk2) {
            bf16x8 ah0 = *(const bf16x8*)&lAh[cur][col][kk2 * 32 + quad * 8];
            bf16x8 ah1 = *(const bf16x8*)&lAh[cur][16 + col][kk2 * 32 + quad * 8];
            acc[0][0] = __builtin_amdgcn_mfma_f32_16x16x32_bf16(ah0, bc[kk2][0], acc[0][0], 0, 0, 0);
            acc[1][0] = __builtin_amdgcn_mfma_f32_16x16x32_bf16(ah1, bc[kk2][0], acc[1][0], 0, 0, 0);
            acc[0][1] = __builtin_amdgcn_mfma_f32_16x16x32_bf16(ah0, bc[kk2][1], acc[0][1], 0, 0, 0);
            acc[1][1] = __builtin_amdgcn_mfma_f32_16x16x32_bf16(ah1, bc[kk2][1], acc[1][1], 0, 0, 0);
            if (it + 2 < NITER) {   // 2-ahead refill into the just-consumed set
                #pragma unroll
                for (int nt = 0; nt < 2; ++nt)
                    bc[kk2][nt] = *(const bf16x8*)(bp[nt] + (it + 2) * BK + kk2 * 32);
            }
        }
        // pin: x refill must be issued AFTER this iter's b refills
        __builtin_amdgcn_sched_barrier(0);
        if (it + 5 < NITER)
            xr = *(const float4*)(xrow + (it + 5) * BK);
        asm volatile("s_waitcnt lgkmcnt(0)" ::: "memory");  // publish A(it+1)
        __builtin_amdgcn_s_barrier();
        asm volatile("" ::: "memory");
    };

    #pragma unroll 1
    for (int itb = 0; itb < NITER; itb += 4) {
        body(itb + 0, r0, b0);
        body(itb + 1, r1, b1);
        body(itb + 2, r2, b0);
        body(itb + 3, r3, b1);
    }

    // ---- epilogue: per-wave top-2 over its 32 experts, per token.
    // C/D layout (16x16): col = lane&15 (expert), row = quad*4 + reg (token).
    #pragma unroll
    for (int mt = 0; mt < 2; ++mt) {
        #pragma unroll
        for (int r = 0; r < 4; ++r) {
            float s0 = acc[mt][0][r]; int e0 = wv * 32 + col;
            float s1 = acc[mt][1][r]; int e1 = e0 + 16;
            float t1s, t2s; int t1e, t2e;
            if (s1 > s0) { t1s = s1; t1e = e1; t2s = s0; t2e = e0; }
            else         { t1s = s0; t1e = e0; t2s = s1; t2e = e1; }
            #pragma unroll
            for (int m = 1; m <= 8; m <<= 1) {
                float o1s = __shfl_xor(t1s, m); int o1e = __shfl_xor(t1e, m);
                float o2s = __shfl_xor(t2s, m); int o2e = __shfl_xor(t2e, m);
                bool o1_top = (o1s > t1s) || (o1s == t1s && o1e < t1e);
                if (o1_top) {
                    bool keep_t1 = (t1s > o2s) || (t1s == o2s && t1e < o2e);
                    t2s = keep_t1 ? t1s : o2s; t2e = keep_t1 ? t1e : o2e;
                    t1s = o1s; t1e = o1e;
                } else {
                    bool o1_2nd = (o1s > t2s) || (o1s == t2s && o1e < t2e);
                    if (o1_2nd) { t2s = o1s; t2e = o1e; }
                }
            }
            if (col == 0) {
                int tok = mt * 16 + quad * 4 + r;
                cand[wv][tok] = make_float4(t1s, __int_as_float(t1e), t2s, __int_as_float(t2e));
            }
        }
    }
    __syncthreads();

    // ---- final merge across waves; write outputs + near-tie flags
    if (tid < MB) {
        float4 c0 = cand[0][tid];
        float t1s = c0.x; int t1e = __float_as_int(c0.y);
        float t2s = c0.z; int t2e = __float_as_int(c0.w);
        #pragma unroll
        for (int wvi = 1; wvi < NWAVES; ++wvi) {
            float4 c = cand[wvi][tid];
            float o1s = c.x; int o1e = __float_as_int(c.y);
            float o2s = c.z; int o2e = __float_as_int(c.w);
            bool o1_top = (o1s > t1s) || (o1s == t1s && o1e < t1e);
            if (o1_top) {
                bool keep_t1 = (t1s > o2s) || (t1s == o2s && t1e < o2e);
                t2s = keep_t1 ? t1s : o2s; t2e = keep_t1 ? t1e : o2e;
                t1s = o1s; t1e = o1e;
            } else {
                bool o1_2nd = (o1s > t2s) || (o1s == t2s && o1e < t2e);
                if (o1_2nd) { t2s = o1s; t2e = o1e; }
            }
        }
        const int gtok = tok0 + tid;
        out[gtok] = 1.0f;                       // STE forward value at argmax
        out[NUM_TOKENS + gtok] = (float)t1e;    // index as float
        if (t1s - t2s < MARGIN) {
            int slot = atomicAdd(counter, 1);
            if (slot < CAP) entries[slot] = make_int4(gtok, t1e, t2e, 0);
        }
    }
}

// ---------------------------------------------------------------- kernel 3
// fp64 re-verification of near-tie tokens (one wave per flagged token).
__global__ void refine(const float* __restrict__ x,
                       const float* __restrict__ w,
                       const int* __restrict__ counter,
                       const int4* __restrict__ entries,
                       float* __restrict__ out) {
    const int gwave  = (blockIdx.x * blockDim.x + threadIdx.x) >> 6;
    const int lane   = threadIdx.x & 63;
    const int nwaves = (gridDim.x * blockDim.x) >> 6;
    int n = *counter; if (n > CAP) n = CAP;
    for (int i = gwave; i < n; i += nwaves) {
        int4 e = entries[i];
        const float* xr = x + (size_t)e.x * DIM;
        const float* w1 = w + (size_t)e.y * DIM;
        const float* w2 = w + (size_t)e.z * DIM;
        double d1 = 0.0, d2 = 0.0;
        for (int k = lane; k < DIM; k += 64) {
            double xv = (double)xr[k];
            d1 += xv * (double)w1[k];
            d2 += xv * (double)w2[k];
        }
        #pragma unroll
        for (int m = 32; m > 0; m >>= 1) {
            d1 += __shfl_xor(d1, m);
            d2 += __shfl_xor(d2, m);
        }
        if (lane == 0) {
            int best = (d1 > d2) ? e.y : ((d2 > d1) ? e.z : (e.y < e.z ? e.y : e.z));
            out[NUM_TOKENS + e.x] = (float)best;
        }
    }
}

// ---------------------------------------------------------------- launcher
extern "C" void kernel_launch(void* const* d_in, const int* in_sizes, int n_in,
                              void* d_out, int out_size, void* d_ws, size_t ws_size,
                              hipStream_t stream) {
    const float* x = (const float*)d_in[0];
    const float* w = (const float*)d_in[1];
    float* out = (float*)d_out;

    char* ws = (char*)d_ws;
    unsigned short* wh = (unsigned short*)ws;                     // 2 MB
    int*  counter = (int*)(ws + (2u << 20));
    int4* entries = (int4*)(ws + (2u << 20) + 16);                // 256 KB

    cvt_weights<<<256, 256, 0, stream>>>(w, wh, counter);
    gate_main<<<NUM_TOKENS / MB, 512, 0, stream>>>(x, wh, out, counter, entries);
    refine<<<256, 256, 0, stream>>>(x, w, counter, entries, out);
}

// Round 5
// 435.515 us; speedup vs baseline: 1.1082x; 1.0613x over previous
//
#include <hip/hip_runtime.h>
#include <stdint.h>

#define NUM_TOKENS 16384
#define DIM        4096
#define NEXP       256
#define MB         64      // tokens per block
#define BK         64      // K per staging step
#define NITER      (DIM / BK)   // 64
#define APAD       72      // A row stride (+8 kills bank conflicts, keeps 16B align)
#define NWAVES     16
#define MARGIN     0.025f  // ~8.6 sigma of the pure-bf16 gap error (std ~2.9e-3)
#define CAP        16384   // refinement list capacity

typedef __attribute__((ext_vector_type(4))) float          f32x4;
typedef __attribute__((ext_vector_type(8))) __bf16         bf16x8;
typedef __attribute__((ext_vector_type(8))) unsigned short ushort8;

static __device__ __forceinline__ unsigned short f32_to_bf16(float f) {
    unsigned int u = __float_as_uint(f);
    u += 0x7fffu + ((u >> 16) & 1u);     // round-to-nearest-even
    return (unsigned short)(u >> 16);
}

// ---------------------------------------------------------------- kernel 1
// Convert + PACK weights fp32 -> bf16 in MFMA-fragment order.
// Packed slot s = ((g*64 + it)*2 + kk2)*64 + lane, 8 elems (16 B) per slot:
//   g = expert group (16 experts), lane = quad*16 + col, expert = g*16+col,
//   k = it*64 + kk2*32 + quad*8.
// A wave's fragment load becomes base + lane*16: fully coalesced, 8
// sequential 128-B lines, zero segment waste (was 16 scattered 64-B
// segments spanning 16 half-used lines).
__global__ void cvt_weights(const float* __restrict__ w,
                            unsigned short* __restrict__ wh,
                            int* __restrict__ counter) {
    if (blockIdx.x == 0 && threadIdx.x == 0) *counter = 0;
    const int n8 = NEXP * DIM / 8;          // 131072 packed slots
    const int stride = gridDim.x * blockDim.x;
    for (int i = blockIdx.x * blockDim.x + threadIdx.x; i < n8; i += stride) {
        // read-coalesced: i enumerates (e, k8) with k fastest
        const int e  = i >> 9;              // DIM/8 = 512 slots per expert
        const int k8 = i & 511;
        const int k  = k8 * 8;
        const int g    = e >> 4;
        const int col  = e & 15;
        const int it   = k8 >> 3;           // k/64
        const int kk2  = (k8 >> 2) & 1;     // (k/32)&1
        const int quad = k8 & 3;            // (k/8)&3
        const int lane = quad * 16 + col;
        const int s    = ((g * 64 + it) * 2 + kk2) * 64 + lane;

        const float* src = w + (size_t)e * DIM + k;
        float4 v0 = *(const float4*)(src);
        float4 v1 = *(const float4*)(src + 4);
        ushort8 h;
        h[0] = f32_to_bf16(v0.x); h[1] = f32_to_bf16(v0.y);
        h[2] = f32_to_bf16(v0.z); h[3] = f32_to_bf16(v0.w);
        h[4] = f32_to_bf16(v1.x); h[5] = f32_to_bf16(v1.y);
        h[6] = f32_to_bf16(v1.z); h[7] = f32_to_bf16(v1.w);
        *(ushort8*)(wh + (size_t)s * 8) = h;
    }
}

// ---------------------------------------------------------------- kernel 2
// R5: cut L2 bytes (the invariant across R1-R4's identical times).
// Diagnosis: 4 different schedules all ~155-198us, pipes <12%, occupancy-
// insensitive -> bound on L2->L1 bytes: B was 64 KB/CU-iter in 64-B
// scattered segments (128 KB effective, half-line waste) + x 16 KB.
// Changes: (1) packed-fragment B (see cvt_weights) - dense sequential
// lines, waste gone; (2) wave = 64 tok x 16 exp (mt=4, nt=1), 16 waves x
// MB=64 - each expert group read by exactly ONE wave, so total B traffic
// halves (1 GB -> 512 MB aggregate). ~144 -> ~48 KB eff/CU-iter.
// Schedule kept from R4 (b ping-pong 2-ahead, x ring 2-deep issued last,
// lgkm-only barriers) since scheduling proved non-limiting.
__global__ __launch_bounds__(1024, 4) void gate_main(
    const float* __restrict__ x,
    const unsigned short* __restrict__ wh,   // PACKED bf16 weights
    float* __restrict__ out,           // [0,T) weights, [T,2T) indices (as float)
    int* __restrict__ counter,
    int4* __restrict__ entries)
{
    __shared__ unsigned short lAh[2][MB][APAD];    // 2 x 9 KB
    __shared__ float4 cand[NWAVES][MB];            // 16 KB

    const int tid  = threadIdx.x;
    const int wv   = tid >> 6;          // wave 0..15 -> experts [wv*16, wv*16+16)
    const int lane = tid & 63;
    const int tok0 = blockIdx.x * MB;

    // A staging: thread covers token ta, 4 floats at kcol
    const int ta   = tid >> 4;          // 0..63
    const int kcol = (tid & 15) * 4;    // 0..60
    const float* xrow = x + (size_t)(tok0 + ta) * DIM + kcol;

    const int quad = lane >> 4;
    const int col  = lane & 15;

    f32x4 acc[4];
    #pragma unroll
    for (int mt = 0; mt < 4; ++mt)
        acc[mt] = f32x4{0.f, 0.f, 0.f, 0.f};

    // packed-B loader: one bf16x8 per kk2, addr = slot*16B, slot as in cvt.
    auto ldb = [&](int it, bf16x8 (&bc)[2]) {
        #pragma unroll
        for (int kk2 = 0; kk2 < 2; ++kk2)
            bc[kk2] = *(const bf16x8*)(wh +
                ((((size_t)wv * 64 + it) * 2 + kk2) * 64 + lane) * 8);
    };

    // ---- prologue. Issue order: b(0), b(1) first, then the x stream.
    bf16x8 bA[2], bB[2];
    ldb(0, bA);
    ldb(1, bB);
    __builtin_amdgcn_sched_barrier(0);
    float4 x0  = *(const float4*)(xrow);             // x(0)
    float4 xva = *(const float4*)(xrow + 1 * BK);    // x(1)
    float4 xvb = *(const float4*)(xrow + 2 * BK);    // x(2)
    {
        ushort4 h;
        h.x = f32_to_bf16(x0.x); h.y = f32_to_bf16(x0.y);
        h.z = f32_to_bf16(x0.z); h.w = f32_to_bf16(x0.w);
        *(ushort4*)&lAh[0][ta][kcol] = h;
    }
    asm volatile("s_waitcnt lgkmcnt(0)" ::: "memory");
    __builtin_amdgcn_s_barrier();
    asm volatile("" ::: "memory");

    // body(it): stage A(it+1) from xr==x(it+1); compute from lAh[it&1] with
    // bc==b(it); refill bc with b(it+2) after use; refill xr = x(it+3) LAST
    // (younger than all b issues -> consuming b never retires a fresh x).
    auto body = [&](int it, float4& xr, bf16x8 (&bc)[2]) {
        const int cur = it & 1;
        const int nxt = cur ^ 1;
        if (it + 1 < NITER) {
            ushort4 h;
            h.x = f32_to_bf16(xr.x); h.y = f32_to_bf16(xr.y);
            h.z = f32_to_bf16(xr.z); h.w = f32_to_bf16(xr.w);
            *(ushort4*)&lAh[nxt][ta][kcol] = h;
        }
        #pragma unroll
        for (int kk2 = 0; kk2 < 2; ++kk2) {
            bf16x8 ah[4];
            #pragma unroll
            for (int mt = 0; mt < 4; ++mt)
                ah[mt] = *(const bf16x8*)&lAh[cur][mt * 16 + col][kk2 * 32 + quad * 8];
            #pragma unroll
            for (int mt = 0; mt < 4; ++mt)
                acc[mt] = __builtin_amdgcn_mfma_f32_16x16x32_bf16(
                    ah[mt], bc[kk2], acc[mt], 0, 0, 0);
        }
        if (it + 2 < NITER)
            ldb(it + 2, bc);            // 2-ahead refill of just-consumed set
        __builtin_amdgcn_sched_barrier(0);  // x refill stays after b refill
        if (it + 3 < NITER)
            xr = *(const float4*)(xrow + (it + 3) * BK);
        asm volatile("s_waitcnt lgkmcnt(0)" ::: "memory");  // publish A(it+1)
        __builtin_amdgcn_s_barrier();
        asm volatile("" ::: "memory");
    };

    #pragma unroll 1
    for (int itb = 0; itb < NITER; itb += 2) {
        body(itb + 0, xva, bA);
        body(itb + 1, xvb, bB);
    }

    // ---- epilogue: per-wave top-2 over its 16 experts, per token.
    // C/D layout (16x16): col = lane&15 (expert), row = quad*4 + reg (token).
    #pragma unroll
    for (int mt = 0; mt < 4; ++mt) {
        #pragma unroll
        for (int r = 0; r < 4; ++r) {
            float t1s = acc[mt][r]; int t1e = wv * 16 + col;
            float t2s = -__builtin_inff(); int t2e = 0x7fffffff;
            #pragma unroll
            for (int m = 1; m <= 8; m <<= 1) {
                float o1s = __shfl_xor(t1s, m); int o1e = __shfl_xor(t1e, m);
                float o2s = __shfl_xor(t2s, m); int o2e = __shfl_xor(t2e, m);
                bool o1_top = (o1s > t1s) || (o1s == t1s && o1e < t1e);
                if (o1_top) {
                    bool keep_t1 = (t1s > o2s) || (t1s == o2s && t1e < o2e);
                    t2s = keep_t1 ? t1s : o2s; t2e = keep_t1 ? t1e : o2e;
                    t1s = o1s; t1e = o1e;
                } else {
                    bool o1_2nd = (o1s > t2s) || (o1s == t2s && o1e < t2e);
                    if (o1_2nd) { t2s = o1s; t2e = o1e; }
                }
            }
            if (col == 0) {
                int tok = mt * 16 + quad * 4 + r;
                cand[wv][tok] = make_float4(t1s, __int_as_float(t1e), t2s, __int_as_float(t2e));
            }
        }
    }
    __syncthreads();

    // ---- final merge across waves; write outputs + near-tie flags
    if (tid < MB) {
        float4 c0 = cand[0][tid];
        float t1s = c0.x; int t1e = __float_as_int(c0.y);
        float t2s = c0.z; int t2e = __float_as_int(c0.w);
        #pragma unroll
        for (int wvi = 1; wvi < NWAVES; ++wvi) {
            float4 c = cand[wvi][tid];
            float o1s = c.x; int o1e = __float_as_int(c.y);
            float o2s = c.z; int o2e = __float_as_int(c.w);
            bool o1_top = (o1s > t1s) || (o1s == t1s && o1e < t1e);
            if (o1_top) {
                bool keep_t1 = (t1s > o2s) || (t1s == o2s && t1e < o2e);
                t2s = keep_t1 ? t1s : o2s; t2e = keep_t1 ? t1e : o2e;
                t1s = o1s; t1e = o1e;
            } else {
                bool o1_2nd = (o1s > t2s) || (o1s == t2s && o1e < t2e);
                if (o1_2nd) { t2s = o1s; t2e = o1e; }
            }
        }
        const int gtok = tok0 + tid;
        out[gtok] = 1.0f;                       // STE forward value at argmax
        out[NUM_TOKENS + gtok] = (float)t1e;    // index as float
        if (t1s - t2s < MARGIN) {
            int slot = atomicAdd(counter, 1);
            if (slot < CAP) entries[slot] = make_int4(gtok, t1e, t2e, 0);
        }
    }
}

// ---------------------------------------------------------------- kernel 3
// fp64 re-verification of near-tie tokens (one wave per flagged token).
// Reads the ORIGINAL fp32 w (unaffected by packing).
__global__ void refine(const float* __restrict__ x,
                       const float* __restrict__ w,
                       const int* __restrict__ counter,
                       const int4* __restrict__ entries,
                       float* __restrict__ out) {
    const int gwave  = (blockIdx.x * blockDim.x + threadIdx.x) >> 6;
    const int lane   = threadIdx.x & 63;
    const int nwaves = (gridDim.x * blockDim.x) >> 6;
    int n = *counter; if (n > CAP) n = CAP;
    for (int i = gwave; i < n; i += nwaves) {
        int4 e = entries[i];
        const float* xr = x + (size_t)e.x * DIM;
        const float* w1 = w + (size_t)e.y * DIM;
        const float* w2 = w + (size_t)e.z * DIM;
        double d1 = 0.0, d2 = 0.0;
        for (int k = lane; k < DIM; k += 64) {
            double xv = (double)xr[k];
            d1 += xv * (double)w1[k];
            d2 += xv * (double)w2[k];
        }
        #pragma unroll
        for (int m = 32; m > 0; m >>= 1) {
            d1 += __shfl_xor(d1, m);
            d2 += __shfl_xor(d2, m);
        }
        if (lane == 0) {
            int best = (d1 > d2) ? e.y : ((d2 > d1) ? e.z : (e.y < e.z ? e.y : e.z));
            out[NUM_TOKENS + e.x] = (float)best;
        }
    }
}

// ---------------------------------------------------------------- launcher
extern "C" void kernel_launch(void* const* d_in, const int* in_sizes, int n_in,
                              void* d_out, int out_size, void* d_ws, size_t ws_size,
                              hipStream_t stream) {
    const float* x = (const float*)d_in[0];
    const float* w = (const float*)d_in[1];
    float* out = (float*)d_out;

    char* ws = (char*)d_ws;
    unsigned short* wh = (unsigned short*)ws;                     // 2 MB packed
    int*  counter = (int*)(ws + (2u << 20));
    int4* entries = (int4*)(ws + (2u << 20) + 16);                // 256 KB

    cvt_weights<<<256, 256, 0, stream>>>(w, wh, counter);
    gate_main<<<NUM_TOKENS / MB, 1024, 0, stream>>>(x, wh, out, counter, entries);
    refine<<<256, 256, 0, stream>>>(x, w, counter, entries, out);
}

// Round 7
// 430.416 us; speedup vs baseline: 1.1214x; 1.0118x over previous
//
#include <hip/hip_runtime.h>
#include <stdint.h>

#define NUM_TOKENS 16384
#define DIM        4096
#define NEXP       256
#define MB         64      // tokens per block
#define BK         256     // K per staging step (FAT iterations: NITER 64 -> 16)
#define NITER      (DIM / BK)   // 16
#define NKK        (BK / 32)    // 8 k32-substeps per iteration
#define AROW       264     // A row stride in ushorts (256 + 8: conflict-free at BW)
#define NWAVES     16
#define MARGIN     0.025f  // ~8.6 sigma of the pure-bf16 gap error (std ~2.9e-3)
#define CAP        16384   // refinement list capacity

typedef __attribute__((ext_vector_type(4))) float          f32x4;
typedef __attribute__((ext_vector_type(8))) __bf16         bf16x8;
typedef __attribute__((ext_vector_type(8))) unsigned short ushort8;

static __device__ __forceinline__ unsigned short f32_to_bf16(float f) {
    unsigned int u = __float_as_uint(f);
    u += 0x7fffu + ((u >> 16) & 1u);     // round-to-nearest-even
    return (unsigned short)(u >> 16);
}

// ---------------------------------------------------------------- kernel 1
// Convert + PACK weights fp32 -> bf16 in MFMA-fragment order.
// Packed slot s = (g*128 + c)*64 + lane, 8 elems (16 B) per slot:
//   g = expert group (16 experts), c = k32 chunk (0..127),
//   lane = quad*16 + col, expert = g*16 + col, k = c*32 + quad*8 + j.
// A wave's fragment load is base + lane*16 B: one dense 1-KB burst.
__global__ void cvt_weights(const float* __restrict__ w,
                            unsigned short* __restrict__ wh,
                            int* __restrict__ counter) {
    if (blockIdx.x == 0 && threadIdx.x == 0) *counter = 0;
    const int n8 = NEXP * DIM / 8;          // 131072 packed slots
    const int stride = gridDim.x * blockDim.x;
    for (int i = blockIdx.x * blockDim.x + threadIdx.x; i < n8; i += stride) {
        const int e  = i >> 9;              // 512 k8-slots per expert
        const int k8 = i & 511;
        const int k  = k8 * 8;
        const int g    = e >> 4;
        const int col  = e & 15;
        const int c    = k8 >> 2;           // k/32
        const int quad = k8 & 3;            // (k/8)&3
        const int lane = quad * 16 + col;
        const int s    = (g * 128 + c) * 64 + lane;

        const float* src = w + (size_t)e * DIM + k;
        float4 v0 = *(const float4*)(src);
        float4 v1 = *(const float4*)(src + 4);
        ushort8 h;
        h[0] = f32_to_bf16(v0.x); h[1] = f32_to_bf16(v0.y);
        h[2] = f32_to_bf16(v0.z); h[3] = f32_to_bf16(v0.w);
        h[4] = f32_to_bf16(v1.x); h[5] = f32_to_bf16(v1.y);
        h[6] = f32_to_bf16(v1.z); h[7] = f32_to_bf16(v1.w);
        *(ushort8*)(wh + (size_t)s * 8) = h;
    }
}

// ---------------------------------------------------------------- kernel 2
// R6 (resubmitted R7: infra failure, never measured). FAT iterations.
// R1-R5 post-mortem: five different schedules all land 150-198us; serial
// sum of ALL pipe work per iter (~3800 cyc) < observed 5625 cyc/iter ->
// the cost is per-ITERATION fixed overhead (barrier convoy + waitcnt
// drains + A publication chain), not throughput. Test: BK 64->256
// (NITER 64->16, one barrier/iter -> 16 barriers total vs 128). Inside an
// iteration: 8 k32-substeps of {2 ds_read + packed-B L2 prefetch + 4 MFMA}
// with no synchronization. Carried from R5: packed-fragment B; wave =
// 32 tok x 32 exp (0.5 KB LDS per MFMA); 16 waves; b ping-pong prefetch;
// x lead = 1 fat iter; lgkm-only barrier (vmem streams stay in flight).
__global__ __launch_bounds__(1024, 4) void gate_main(
    const float* __restrict__ x,
    const unsigned short* __restrict__ wh,   // PACKED bf16 weights
    float* __restrict__ out,           // [0,T) weights, [T,2T) indices (as float)
    int* __restrict__ counter,
    int4* __restrict__ entries)
{
    __shared__ unsigned short lAh[2][MB][AROW];    // 2 x 33 KB
    __shared__ float4 cand[8][MB];                 // 8 KB (expert-octant x token)

    const int tid  = threadIdx.x;
    const int wv   = tid >> 6;          // wave 0..15
    const int lane = tid & 63;
    const int tok0 = blockIdx.x * MB;

    // wave tiling: token half th = wv&1 (32 tokens), expert octant ewv = wv>>1
    const int th  = wv & 1;
    const int ewv = wv >> 1;            // experts [ewv*32, ewv*32+32)

    // A staging: thread covers token ta, 16 floats at kc16
    const int ta   = tid >> 4;          // 0..63
    const int kc16 = (tid & 15) * 16;   // 0..240
    const float* xrow = x + (size_t)(tok0 + ta) * DIM + kc16;

    const int quad = lane >> 4;
    const int col  = lane & 15;

    f32x4 acc[2][2];                    // [mt][nt]
    #pragma unroll
    for (int mt = 0; mt < 2; ++mt)
        #pragma unroll
        for (int nt = 0; nt < 2; ++nt)
            acc[mt][nt] = f32x4{0.f, 0.f, 0.f, 0.f};

    // packed-B loader for k32-chunk c: group g = ewv*2 + nt
    auto ldb = [&](int c, bf16x8 (&bc)[2]) {
        #pragma unroll
        for (int nt = 0; nt < 2; ++nt)
            bc[nt] = *(const bf16x8*)(wh +
                (((size_t)(ewv * 2 + nt) * 128 + c) * 64 + lane) * 8);
    };

    struct XQ { float4 a, b, c, d; };
    auto ldx = [&](int it) {
        XQ v;
        const float* p = xrow + it * BK;
        v.a = *(const float4*)(p);
        v.b = *(const float4*)(p + 4);
        v.c = *(const float4*)(p + 8);
        v.d = *(const float4*)(p + 12);
        return v;
    };
    auto stageA = [&](int slot, const XQ& v) {
        ushort8 h0, h1;
        h0[0] = f32_to_bf16(v.a.x); h0[1] = f32_to_bf16(v.a.y);
        h0[2] = f32_to_bf16(v.a.z); h0[3] = f32_to_bf16(v.a.w);
        h0[4] = f32_to_bf16(v.b.x); h0[5] = f32_to_bf16(v.b.y);
        h0[6] = f32_to_bf16(v.b.z); h0[7] = f32_to_bf16(v.b.w);
        h1[0] = f32_to_bf16(v.c.x); h1[1] = f32_to_bf16(v.c.y);
        h1[2] = f32_to_bf16(v.c.z); h1[3] = f32_to_bf16(v.c.w);
        h1[4] = f32_to_bf16(v.d.x); h1[5] = f32_to_bf16(v.d.y);
        h1[6] = f32_to_bf16(v.d.z); h1[7] = f32_to_bf16(v.d.w);
        *(ushort8*)&lAh[slot][ta][kc16]     = h0;
        *(ushort8*)&lAh[slot][ta][kc16 + 8] = h1;
    };

    // ---- prologue: A(0) staged, x(1) in regs, b(c=0) in regs.
    XQ xq = ldx(0);
    stageA(0, xq);
    xq = ldx(1);
    bf16x8 bA[2], bB[2];
    ldb(0, bA);
    asm volatile("s_waitcnt lgkmcnt(0)" ::: "memory");
    __builtin_amdgcn_s_barrier();
    __builtin_amdgcn_sched_barrier(0);

    #pragma unroll 1
    for (int it = 0; it < NITER; ++it) {
        const int cur = it & 1;
        const int nxt = cur ^ 1;
        // stage A(it+1); refill xq = x(it+2). x is issued before this iter's
        // b prefetches, so next iter's A-write wait only retires consumed b's.
        if (it + 1 < NITER) {
            stageA(nxt, xq);
            if (it + 2 < NITER)
                xq = ldx(it + 2);
        }
        // 8 k32-substeps, no sync inside; b ping-pong 1-ahead from packed L2
        #pragma unroll
        for (int kk = 0; kk < NKK; ++kk) {
            bf16x8 (&bc)[2] = (kk & 1) ? bB : bA;
            bf16x8 (&bn)[2] = (kk & 1) ? bA : bB;
            const int c = it * NKK + kk;
            if (c + 1 < DIM / 32)
                ldb(c + 1, bn);
            bf16x8 ah0 = *(const bf16x8*)&lAh[cur][th * 32 + col][kk * 32 + quad * 8];
            bf16x8 ah1 = *(const bf16x8*)&lAh[cur][th * 32 + 16 + col][kk * 32 + quad * 8];
            acc[0][0] = __builtin_amdgcn_mfma_f32_16x16x32_bf16(ah0, bc[0], acc[0][0], 0, 0, 0);
            acc[1][0] = __builtin_amdgcn_mfma_f32_16x16x32_bf16(ah1, bc[0], acc[1][0], 0, 0, 0);
            acc[0][1] = __builtin_amdgcn_mfma_f32_16x16x32_bf16(ah0, bc[1], acc[0][1], 0, 0, 0);
            acc[1][1] = __builtin_amdgcn_mfma_f32_16x16x32_bf16(ah1, bc[1], acc[1][1], 0, 0, 0);
        }
        asm volatile("s_waitcnt lgkmcnt(0)" ::: "memory");  // publish A(it+1)
        __builtin_amdgcn_s_barrier();
        __builtin_amdgcn_sched_barrier(0);
    }

    // ---- epilogue: per-wave top-2 over its 32 experts, per token.
    // C/D layout (16x16): col = lane&15 (expert), row = quad*4 + reg (token).
    #pragma unroll
    for (int mt = 0; mt < 2; ++mt) {
        #pragma unroll
        for (int r = 0; r < 4; ++r) {
            float s0 = acc[mt][0][r]; int e0 = ewv * 32 + col;
            float s1 = acc[mt][1][r]; int e1 = e0 + 16;
            float t1s, t2s; int t1e, t2e;
            if (s1 > s0) { t1s = s1; t1e = e1; t2s = s0; t2e = e0; }
            else         { t1s = s0; t1e = e0; t2s = s1; t2e = e1; }
            #pragma unroll
            for (int m = 1; m <= 8; m <<= 1) {
                float o1s = __shfl_xor(t1s, m); int o1e = __shfl_xor(t1e, m);
                float o2s = __shfl_xor(t2s, m); int o2e = __shfl_xor(t2e, m);
                bool o1_top = (o1s > t1s) || (o1s == t1s && o1e < t1e);
                if (o1_top) {
                    bool keep_t1 = (t1s > o2s) || (t1s == o2s && t1e < o2e);
                    t2s = keep_t1 ? t1s : o2s; t2e = keep_t1 ? t1e : o2e;
                    t1s = o1s; t1e = o1e;
                } else {
                    bool o1_2nd = (o1s > t2s) || (o1s == t2s && o1e < t2e);
                    if (o1_2nd) { t2s = o1s; t2e = o1e; }
                }
            }
            if (col == 0) {
                int tok = th * 32 + mt * 16 + quad * 4 + r;
                cand[ewv][tok] = make_float4(t1s, __int_as_float(t1e), t2s, __int_as_float(t2e));
            }
        }
    }
    __syncthreads();

    // ---- final merge across expert octants; write outputs + near-tie flags
    if (tid < MB) {
        float4 c0 = cand[0][tid];
        float t1s = c0.x; int t1e = __float_as_int(c0.y);
        float t2s = c0.z; int t2e = __float_as_int(c0.w);
        #pragma unroll
        for (int e = 1; e < 8; ++e) {
            float4 c = cand[e][tid];
            float o1s = c.x; int o1e = __float_as_int(c.y);
            float o2s = c.z; int o2e = __float_as_int(c.w);
            bool o1_top = (o1s > t1s) || (o1s == t1s && o1e < t1e);
            if (o1_top) {
                bool keep_t1 = (t1s > o2s) || (t1s == o2s && t1e < o2e);
                t2s = keep_t1 ? t1s : o2s; t2e = keep_t1 ? t1e : o2e;
                t1s = o1s; t1e = o1e;
            } else {
                bool o1_2nd = (o1s > t2s) || (o1s == t2s && o1e < t2e);
                if (o1_2nd) { t2s = o1s; t2e = o1e; }
            }
        }
        const int gtok = tok0 + tid;
        out[gtok] = 1.0f;                       // STE forward value at argmax
        out[NUM_TOKENS + gtok] = (float)t1e;    // index as float
        if (t1s - t2s < MARGIN) {
            int slot = atomicAdd(counter, 1);
            if (slot < CAP) entries[slot] = make_int4(gtok, t1e, t2e, 0);
        }
    }
}

// ---------------------------------------------------------------- kernel 3
// fp64 re-verification of near-tie tokens (one wave per flagged token).
// Reads the ORIGINAL fp32 w (unaffected by packing).
__global__ void refine(const float* __restrict__ x,
                       const float* __restrict__ w,
                       const int* __restrict__ counter,
                       const int4* __restrict__ entries,
                       float* __restrict__ out) {
    const int gwave  = (blockIdx.x * blockDim.x + threadIdx.x) >> 6;
    const int lane   = threadIdx.x & 63;
    const int nwaves = (gridDim.x * blockDim.x) >> 6;
    int n = *counter; if (n > CAP) n = CAP;
    for (int i = gwave; i < n; i += nwaves) {
        int4 e = entries[i];
        const float* xr = x + (size_t)e.x * DIM;
        const float* w1 = w + (size_t)e.y * DIM;
        const float* w2 = w + (size_t)e.z * DIM;
        double d1 = 0.0, d2 = 0.0;
        for (int k = lane; k < DIM; k += 64) {
            double xv = (double)xr[k];
            d1 += xv * (double)w1[k];
            d2 += xv * (double)w2[k];
        }
        #pragma unroll
        for (int m = 32; m > 0; m >>= 1) {
            d1 += __shfl_xor(d1, m);
            d2 += __shfl_xor(d2, m);
        }
        if (lane == 0) {
            int best = (d1 > d2) ? e.y : ((d2 > d1) ? e.z : (e.y < e.z ? e.y : e.z));
            out[NUM_TOKENS + e.x] = (float)best;
        }
    }
}

// ---------------------------------------------------------------- launcher
extern "C" void kernel_launch(void* const* d_in, const int* in_sizes, int n_in,
                              void* d_out, int out_size, void* d_ws, size_t ws_size,
                              hipStream_t stream) {
    const float* x = (const float*)d_in[0];
    const float* w = (const float*)d_in[1];
    float* out = (float*)d_out;

    char* ws = (char*)d_ws;
    unsigned short* wh = (unsigned short*)ws;                     // 2 MB packed
    int*  counter = (int*)(ws + (2u << 20));
    int4* entries = (int4*)(ws + (2u << 20) + 16);                // 256 KB

    cvt_weights<<<256, 256, 0, stream>>>(w, wh, counter);
    gate_main<<<NUM_TOKENS / MB, 1024, 0, stream>>>(x, wh, out, counter, entries);
    refine<<<256, 256, 0, stream>>>(x, w, counter, entries, out);
}